// Round 5
// baseline (209.331 us; speedup 1.0000x reference)
//
#include <hip/hip_runtime.h>
#include <hip/hip_bf16.h>
#include <math.h>

#define B_ 2
#define D_ 256
#define N_ 8192
#define CI_ 128
#define M_ 4096
#define BN_EPS_ 1e-5f
#define LOG2E_ 1.4426950408889634f

#define GLOBAL_AS __attribute__((address_space(1)))
#define LDS_AS __attribute__((address_space(3)))

// ---- workspace layout (float offsets) ----
#define OFF_WALL 0                          // bf16 wall[384][256] + wall2[256][128]
#define OFF_THT  65536                      // theta bf16 [B][N][CI]  (pre-scaled by log2 e)
#define OFF_PHT  (OFF_THT + 1048576)        // phi   bf16 [B][M][CI]
#define OFF_GT   (OFF_PHT + 524288)         // g     bf16 [B][CI][M]
#define OFF_YP   (OFF_GT  + 524288)         // y partial bf16 [4][B][N][CI]  (TRANSPOSED)
#define OFF_ML   (OFF_YP  + 4194304)        // m/l fp32 [4][B][2][N]  (m in log2 domain)
#define OFF_MEAN (OFF_ML + 131072)
#define OFF_RSTD (OFF_MEAN + 256)

typedef __attribute__((ext_vector_type(8))) short bfrag;    // 8 bf16 = 4 VGPRs
typedef __attribute__((ext_vector_type(4))) float f4v;      // 16x16 accumulator
typedef __attribute__((ext_vector_type(16))) float f16v;    // 32x32 accumulator
typedef __attribute__((ext_vector_type(4))) short s4v;      // 4 bf16
typedef __attribute__((ext_vector_type(4))) unsigned u4v;   // 4 dwords (reg-only frag build)

__device__ inline unsigned short bf16rne(float x) {
    unsigned u = __float_as_uint(x);
    u += 0x7fff + ((u >> 16) & 1);
    return (unsigned short)(u >> 16);
}

// 2^x via v_exp_f32 directly (no ocml denorm path, no log2e mul)
__device__ inline float exp2fast(float x) {
    float r;
    asm("v_exp_f32 %0, %1" : "=v"(r) : "v"(x));
    return r;
}

// ---------------- pack weights to bf16: wall[384][256] (g|theta|phi), wall2[256][128] (W) ----
// theta weights are pre-scaled by log2(e) so attention softmax runs in exp2 domain.
__global__ __launch_bounds__(256) void wconv_kernel(
    const float* __restrict__ gw, const float* __restrict__ tw, const float* __restrict__ pw,
    const float* __restrict__ Ww, short* __restrict__ wall)
{
    int idx = blockIdx.x * 256 + threadIdx.x;      // 0 .. 131071
    int which = idx >> 15;
    int rem = idx & 32767;
    const float* src = (which == 0) ? gw : (which == 1) ? tw : (which == 2) ? pw : Ww;
    float v = src[rem];
    if (which == 1) v *= LOG2E_;
    wall[idx] = (short)bf16rne(v);
}

// ---------------- MFMA projections ----------------
// Out[cc][n] = sum_d Wall[cc][d] * f[b][d][n], cc in [0,384): g | theta | phi.
// block 256 = 4 waves; wave owns 96 cc (6 frags) x 32 n (2 frags). grid (N/32, B).
__global__ __launch_bounds__(256, 2) void proj_kernel(
    const float* __restrict__ f, const short* __restrict__ wall,
    const float* __restrict__ tb, const float* __restrict__ gb, const float* __restrict__ pb,
    short* __restrict__ th_t, short* __restrict__ g_t, short* __restrict__ ph_t)
{
    __shared__ short sF[32 * 72];   // f chunk transposed [n][k], stride 72 shorts

    const int tid = threadIdx.x;
    const int wave = tid >> 6, lane = tid & 63;
    const int lq = lane & 15, quad = lane >> 4;
    const int b = blockIdx.y;
    const int n0 = blockIdx.x * 32;

    const float* fb = f + (size_t)b * D_ * N_;

    f4v acc[6][2];
#pragma unroll
    for (int ct = 0; ct < 6; ct++)
#pragma unroll
        for (int nf = 0; nf < 2; nf++) acc[ct][nf] = (f4v){0.f, 0.f, 0.f, 0.f};

    const int sn = tid & 31;     // staging: n within tile
    const int sgrp = tid >> 5;   // staging: d' group of 8

    for (int kc = 0; kc < D_; kc += 64) {
        __syncthreads();
#pragma unroll
        for (int jj = 0; jj < 4; jj++) {
            int dd = kc + sgrp * 8 + 2 * jj;
            float v0 = fb[(size_t)dd * N_ + n0 + sn];
            float v1 = fb[(size_t)(dd + 1) * N_ + n0 + sn];
            unsigned pk = (unsigned)bf16rne(v0) | ((unsigned)bf16rne(v1) << 16);
            *(unsigned*)&sF[sn * 72 + sgrp * 8 + 2 * jj] = pk;
        }
        __syncthreads();

        bfrag afr[6][2], bfr[2][2];
#pragma unroll
        for (int ks = 0; ks < 2; ks++) {
#pragma unroll
            for (int nf = 0; nf < 2; nf++)
                bfr[nf][ks] = *(const bfrag*)&sF[(nf * 16 + lq) * 72 + ks * 32 + quad * 8];
#pragma unroll
            for (int ct = 0; ct < 6; ct++)
                afr[ct][ks] = *(const bfrag*)&wall[(wave * 96 + ct * 16 + lq) * 256 + kc + ks * 32 + quad * 8];
        }
#pragma unroll
        for (int ks = 0; ks < 2; ks++)
#pragma unroll
            for (int ct = 0; ct < 6; ct++) {
                acc[ct][0] = __builtin_amdgcn_mfma_f32_16x16x32_bf16(afr[ct][ks], bfr[0][ks], acc[ct][0], 0, 0, 0);
                acc[ct][1] = __builtin_amdgcn_mfma_f32_16x16x32_bf16(afr[ct][ks], bfr[1][ks], acc[ct][1], 0, 0, 0);
            }
    }

#pragma unroll
    for (int ct = 0; ct < 6; ct++) {
        const int cf = wave * 6 + ct;
#pragma unroll
        for (int nf = 0; nf < 2; nf++) {
            f4v v = acc[ct][nf];
            const int n = n0 + nf * 16 + lq;
            if (cf < 8) {                 // g -> pooled, transposed [c][m]
                const int cb = cf * 16 + quad * 4;
                float pl[4];
#pragma unroll
                for (int r = 0; r < 4; r++) {
                    float o = __shfl_xor(v[r], 1);
                    pl[r] = fmaxf(v[r], o) + gb[cb + r];
                }
                if (!(lq & 1)) {
                    const int m = n >> 1;
#pragma unroll
                    for (int r = 0; r < 4; r++)
                        g_t[((size_t)b * CI_ + cb + r) * M_ + m] = (short)bf16rne(pl[r]);
                }
            } else if (cf < 16) {         // theta [n][c], log2e-scaled (weights already scaled)
                const int cb = (cf - 8) * 16 + quad * 4;
                s4v o;
#pragma unroll
                for (int r = 0; r < 4; r++) o[r] = (short)bf16rne(v[r] + tb[cb + r] * LOG2E_);
                *(s4v*)&th_t[((size_t)b * N_ + n) * CI_ + cb] = o;
            } else {                      // phi -> pooled [m][c]
                const int cb = (cf - 16) * 16 + quad * 4;
                float pl[4];
#pragma unroll
                for (int r = 0; r < 4; r++) {
                    float o = __shfl_xor(v[r], 1);
                    pl[r] = fmaxf(v[r], o) + pb[cb + r];
                }
                if (!(lq & 1)) {
                    const int m = n >> 1;
                    s4v o;
#pragma unroll
                    for (int r = 0; r < 4; r++) o[r] = (short)bf16rne(pl[r]);
                    *(s4v*)&ph_t[((size_t)b * M_ + m) * CI_ + cb] = o;
                }
            }
        }
    }
}

// ---------------- MFMA flash attention, 32x32 tiles, key-split 4 ----------------
// block 256 = 4 waves; wave owns 32 q. Q-tile 128, KC=64 keys/chunk, 16 chunks.
// R3 postmortem: LDS pipe was the largest shared resource (8 waves x 32 b128/chunk)
// and sG's [128][64] layout had a 4-way bank conflict (2.1M cycles). R4: sG REMOVED —
// all 4 waves read identical g data, so each lane now loads its 16 ga fragments
// directly from global (L1-resident 16 KB chunk, XCD-pinned L2 behind it) at chunk
// top; consumed in PV ~600 cyc later. LDS = sPh only (32 KB), conflict-free reads.
// yp written TRANSPOSED [sp][b][n][c] with 8B stores (feeds vectorized merge).
__global__ __launch_bounds__(256, 2) void attn_kernel(
    const short* __restrict__ th_p, const short* __restrict__ ph_p,
    const short* __restrict__ g_p, short* __restrict__ yp, float* __restrict__ ml)
{
    __shared__ short sPh[2][64 * 128];  // phi [key][ci], 256B rows, XOR-16 swizzled slots

    const int tid = threadIdx.x;
    const int wave = tid >> 6, lane = tid & 63;
    const int l = lane & 31, h = lane >> 5;

    // XCD-pinned decomposition: consecutive block ids round-robin across the 8
    // XCDs, and we have exactly 8 (b,split) pairs -> pin pair = bid&7.
    const int bid = blockIdx.x;
    const int b = bid & 1;
    const int split = (bid >> 1) & 3;
    const int q0 = (bid >> 3) * 128;
    const int qg = q0 + wave * 32 + l;

    // theta B-fragments in registers: B[k = 16s + 8h + j][n = q]
    const short* thr = th_p + ((size_t)b * N_ + qg) * CI_;
    bfrag tf[8];
#pragma unroll
    for (int s = 0; s < 8; s++)
        tf[s] = *(const bfrag*)&thr[s * 16 + h * 8];

    f16v yacc[4];
#pragma unroll
    for (int ct = 0; ct < 4; ct++)
#pragma unroll
        for (int r = 0; r < 16; r++) yacc[ct][r] = 0.f;
    float mI = -INFINITY, lI = 0.f;

    const short* phg = ph_p + (size_t)b * M_ * CI_;
    const short* gg  = g_p + (size_t)b * CI_ * M_;

    const int k0 = split * 1024;
    const int xm = l & 15;               // read-side swizzle mask for sPh

    // DMA staging (phi only): per wave 4 issues x (64 lanes x 16B) = 16 rows.
    // HW writes LDS at uniform base + lane*16; global src carries the swizzle.
    const int prow = (lane >> 4);        // phi: row-within-4-group
    const int pslot = lane & 15;         // phi: 16B slot

#define STAGE_DMA(BUF, KC)                                                                  \
    do {                                                                                    \
        _Pragma("unroll")                                                                   \
        for (int p = 0; p < 4; p++) {                                                       \
            const int rp = wave * 16 + p * 4 + prow;          /* row in [0,64) */           \
            const int cg = pslot ^ (p * 4 + prow);            /* swizzled ci-group */       \
            __builtin_amdgcn_global_load_lds(                                               \
                (const GLOBAL_AS void*)(phg + (size_t)((KC) + rp) * 128 + cg * 8),          \
                (LDS_AS void*)(&sPh[BUF][(wave * 16 + p * 4) * 128]), 16, 0, 0);            \
        }                                                                                   \
    } while (0)

    STAGE_DMA(0, k0);

    int cur = 0;
    for (int kc = k0; kc < k0 + 1024; kc += 64) {
        __syncthreads();                 // drains DMA vmcnt; buf[cur] complete for all waves
        const bool nxt = (kc + 64 < k0 + 1024);

        // g fragments for this chunk: ga[ct][s][j] = g^T[c = ct*32+l][kc + 16s + 8h + j].
        // Issued now (VMEM pipe), consumed in PV after QK+softmax -> latency hidden.
        bfrag ga[4][4];
#pragma unroll
        for (int ct = 0; ct < 4; ct++)
#pragma unroll
            for (int s = 0; s < 4; s++)
                ga[ct][s] = *(const bfrag*)&gg[(size_t)(ct * 32 + l) * M_ + kc + s * 16 + h * 8];

        if (nxt) STAGE_DMA(cur ^ 1, kc + 64);    // in-flight across this chunk's compute
        __builtin_amdgcn_sched_barrier(0);       // pin all VMEM issues before the MFMA region

        // S^T = phi . theta : 2 key-tiles of 32; lane holds col q = l, 16 key-rows/tile
        f16v sv[2];
        __builtin_amdgcn_s_setprio(1);
#pragma unroll
        for (int kt = 0; kt < 2; kt++) {
            f16v a;
#pragma unroll
            for (int r = 0; r < 16; r++) a[r] = 0.f;
#pragma unroll
            for (int s = 0; s < 8; s++) {
                bfrag pa = *(const bfrag*)&sPh[cur][(kt * 32 + l) * 128 + (((s << 1) | h) ^ xm) * 8];
                a = __builtin_amdgcn_mfma_f32_32x32x16_bf16(pa, tf[s], a, 0, 0, 0);
            }
            sv[kt] = a;
        }
        __builtin_amdgcn_s_setprio(0);

        // online softmax for q = l, exp2 domain (keys split across h halves: one shfl)
        float mx = fmaxf(sv[0][0], sv[1][0]);
#pragma unroll
        for (int r = 1; r < 16; r++) mx = fmaxf(mx, fmaxf(sv[0][r], sv[1][r]));
        mx = fmaxf(mx, __shfl_xor(mx, 32));

        // defer-max: only rescale when the running max grew by > 8 (p bounded by 2^8)
        if (__any(mx > mI + 8.f)) {
            float mnew = fmaxf(mI, mx);
            float al = exp2fast(mI - mnew);
            lI *= al;
#pragma unroll
            for (int ct = 0; ct < 4; ct++)
#pragma unroll
                for (int r = 0; r < 16; r++) yacc[ct][r] *= al;
            mI = mnew;
        }

        float ps = 0.f;
        // pack exp2(S) pairs: pw[kt*8 + b2*2 + p] holds keys kt*32 + 8*b2 + 4h + 2p + {0,1}
        unsigned pw[16];
#pragma unroll
        for (int kt = 0; kt < 2; kt++)
#pragma unroll
            for (int i = 0; i < 8; i++) {
                const int r = 2 * i;
                float p0 = exp2fast(sv[kt][r] - mI);
                float p1 = exp2fast(sv[kt][r + 1] - mI);
                ps += p0 + p1;
                unsigned pk;
                asm("v_cvt_pk_bf16_f32 %0, %1, %2" : "=v"(pk) : "v"(p0), "v"(p1));
                pw[kt * 8 + (i >> 1) * 2 + (i & 1)] = pk;
            }
        ps += __shfl_xor(ps, 32);
        lI += ps;

        // P -> B-operand frags: pf[s][j] = P[key = 16s + 8h + j][q = l].
        // value with key k: held at half bit2(k), needed at half bit3(k) -> one shfl_xor(32).
        // All pw[] indices are compile-time constants; h only selects VALUES (cndmask).
        // Register-only build: ext_vector element writes + bit_cast (NO union/address).
        bfrag pf[4];
#pragma unroll
        for (int s = 0; s < 4; s++) {
            const int kt = s >> 1;
            const int iA = kt * 8 + ((2 * s) & 3) * 2;       // block used when h==0 as "own"
            const int iB = kt * 8 + ((2 * s + 1) & 3) * 2;   // block used when h==1 as "own"
            unsigned A0 = pw[iA], A1 = pw[iA + 1];
            unsigned B0 = pw[iB], B1 = pw[iB + 1];
            unsigned O0 = h ? B0 : A0;
            unsigned O1 = h ? B1 : A1;
            unsigned Xs0 = h ? A0 : B0;
            unsigned Xs1 = h ? A1 : B1;
            unsigned X0 = (unsigned)__shfl_xor((int)Xs0, 32);
            unsigned X1 = (unsigned)__shfl_xor((int)Xs1, 32);
            u4v t;
            t.x = h ? X0 : O0;
            t.y = h ? X1 : O1;
            t.z = h ? O0 : X0;
            t.w = h ? O1 : X1;
            pf[s] = __builtin_bit_cast(bfrag, t);
        }

        // PV: y^T += g^T . P  (g from registers, no LDS)
        __builtin_amdgcn_s_setprio(1);
#pragma unroll
        for (int ct = 0; ct < 4; ct++)
#pragma unroll
            for (int s = 0; s < 4; s++)
                yacc[ct] = __builtin_amdgcn_mfma_f32_32x32x16_bf16(ga[ct][s], pf[s], yacc[ct], 0, 0, 0);
        __builtin_amdgcn_s_setprio(0);

        cur ^= 1;
    }
#undef STAGE_DMA

    // epilogue: bf16 unnormalized partials TRANSPOSED [n][c] (8B stores) + (m,l)
    short* yb = yp + (((size_t)split * B_ + b) * N_) * CI_;
#pragma unroll
    for (int ct = 0; ct < 4; ct++)
#pragma unroll
        for (int rq = 0; rq < 4; rq++) {
            const int c0 = ct * 32 + 8 * rq + 4 * h;
            s4v o;
#pragma unroll
            for (int j = 0; j < 4; j++) o[j] = (short)bf16rne(yacc[ct][rq * 4 + j]);
            *(s4v*)&yb[(size_t)qg * CI_ + c0] = o;
        }
    if (h == 0) {
        float* mlb = ml + ((split * B_ + b) * 2) * N_;
        mlb[qg] = mI;
        mlb[N_ + qg] = lI;
    }
}

// ---------------- fused merge(4 splits) + Wy MFMA + bias -> d_out ----------------
// out[b][d][n] = Wb[d] + sum_c W[d][c] * y_merged[c][n].
// grid (N/32, B), block 256 = 4 waves; wave w owns d-tiles {2w,2w+1} x 32 n.
// yp is [sp][b][n][c]: per (sp,s) one bfrag (16B) load -> 32 vector loads/thread
// (was 256 scalar ushort loads).
__global__ __launch_bounds__(256) void wy_merge_kernel(
    const short* __restrict__ yp, const float* __restrict__ ml,
    const short* __restrict__ wall2, const float* __restrict__ Wb,
    float* __restrict__ out)
{
    const int tid = threadIdx.x;
    const int wave = tid >> 6, lane = tid & 63;
    const int l = lane & 31, h = lane >> 5;
    const int b = blockIdx.y;
    const int n = blockIdx.x * 32 + l;

    // merge coefficients for this lane's n (m values are log2-domain)
    float m[4], lv[4];
#pragma unroll
    for (int sp = 0; sp < 4; sp++) {
        const float* mlb = ml + ((sp * B_ + b) * 2) * N_;
        m[sp] = mlb[n];
        lv[sp] = mlb[N_ + n];
    }
    float mmax = fmaxf(fmaxf(m[0], m[1]), fmaxf(m[2], m[3]));
    float e[4], den = 0.f;
#pragma unroll
    for (int sp = 0; sp < 4; sp++) { e[sp] = exp2fast(m[sp] - mmax); den += lv[sp] * e[sp]; }
    float inv = 1.0f / den;
#pragma unroll
    for (int sp = 0; sp < 4; sp++) e[sp] *= inv;

    // B-fragments: by[s][j] = y_merged[c = 16s + 8h + j][n]  (vector bfrag loads)
    bfrag by[8];
#pragma unroll
    for (int s = 0; s < 8; s++) {
        float a[8];
#pragma unroll
        for (int j = 0; j < 8; j++) a[j] = 0.f;
#pragma unroll
        for (int sp = 0; sp < 4; sp++) {
            bfrag yv = *(const bfrag*)&yp[(((size_t)sp * B_ + b) * N_ + n) * CI_ + s * 16 + h * 8];
            u4v u = __builtin_bit_cast(u4v, yv);
#pragma unroll
            for (int p = 0; p < 4; p++) {
                a[2 * p]     = fmaf(e[sp], __uint_as_float(u[p] << 16), a[2 * p]);
                a[2 * p + 1] = fmaf(e[sp], __uint_as_float(u[p] & 0xffff0000u), a[2 * p + 1]);
            }
        }
        u4v pk;
#pragma unroll
        for (int p = 0; p < 4; p++) {
            unsigned r;
            asm("v_cvt_pk_bf16_f32 %0, %1, %2" : "=v"(r) : "v"(a[2 * p]), "v"(a[2 * p + 1]));
            pk[p] = r;
        }
        by[s] = __builtin_bit_cast(bfrag, pk);
    }

    f16v acc[2];
#pragma unroll
    for (int rt = 0; rt < 2; rt++)
#pragma unroll
        for (int r = 0; r < 16; r++) acc[rt][r] = 0.f;

#pragma unroll
    for (int s = 0; s < 8; s++)
#pragma unroll
        for (int rt = 0; rt < 2; rt++) {
            bfrag aw = *(const bfrag*)&wall2[((wave * 2 + rt) * 32 + l) * 128 + s * 16 + h * 8];
            acc[rt] = __builtin_amdgcn_mfma_f32_32x32x16_bf16(aw, by[s], acc[rt], 0, 0, 0);
        }

#pragma unroll
    for (int rt = 0; rt < 2; rt++)
#pragma unroll
        for (int r = 0; r < 16; r++) {
            const int d = (wave * 2 + rt) * 32 + (r & 3) + 8 * (r >> 2) + 4 * h;
            out[((size_t)b * D_ + d) * N_ + n] = acc[rt][r] + Wb[d];
        }
}

// ---------------- per-channel batch stats over (b, n) ----------------
__global__ __launch_bounds__(256) void stats_kernel(
    const float* __restrict__ wy, float* __restrict__ mean, float* __restrict__ rstd)
{
    __shared__ float ssum[256], ssq[256];
    int d = blockIdx.x;
    int tid = threadIdx.x;
    float s = 0.f, sq = 0.f;
    for (int b = 0; b < B_; b++) {
        const float4* p = (const float4*)(wy + (size_t)b * D_ * N_ + (size_t)d * N_);
        for (int i = tid; i < N_ / 4; i += 256) {
            float4 v = p[i];
            s += v.x + v.y + v.z + v.w;
            sq = fmaf(v.x, v.x, sq);
            sq = fmaf(v.y, v.y, sq);
            sq = fmaf(v.z, v.z, sq);
            sq = fmaf(v.w, v.w, sq);
        }
    }
    ssum[tid] = s; ssq[tid] = sq;
    __syncthreads();
    for (int st = 128; st > 0; st >>= 1) {
        if (tid < st) { ssum[tid] += ssum[tid + st]; ssq[tid] += ssq[tid + st]; }
        __syncthreads();
    }
    if (tid == 0) {
        float inv = 1.0f / (float)(B_ * N_);
        float mn = ssum[0] * inv;
        float var = ssq[0] * inv - mn * mn;
        mean[d] = mn;
        rstd[d] = rsqrtf(var + BN_EPS_);
    }
}

// ---------------- BN (affine) + residual, in-place on d_out ----------------
__global__ __launch_bounds__(256) void bn_res_kernel(
    float* __restrict__ out, const float* __restrict__ f,
    const float* __restrict__ mean, const float* __restrict__ rstd,
    const float* __restrict__ gamma, const float* __restrict__ beta)
{
    int i = blockIdx.x * 256 + threadIdx.x;
    size_t e = (size_t)i * 4;
    int d = (int)((e >> 13) & 255);
    float4 wy = ((const float4*)out)[i];
    float4 ff = ((const float4*)f)[i];
    float sc = rstd[d] * gamma[d];
    float mn = mean[d];
    float bt = beta[d];
    float4 r;
    r.x = (wy.x - mn) * sc + bt + ff.x;
    r.y = (wy.y - mn) * sc + bt + ff.y;
    r.z = (wy.z - mn) * sc + bt + ff.z;
    r.w = (wy.w - mn) * sc + bt + ff.w;
    ((float4*)out)[i] = r;
}

extern "C" void kernel_launch(void* const* d_in, const int* in_sizes, int n_in,
                              void* d_out, int out_size, void* d_ws, size_t ws_size,
                              hipStream_t stream)
{
    const float* f   = (const float*)d_in[0];
    const float* g_w = (const float*)d_in[1];
    const float* g_b = (const float*)d_in[2];
    const float* t_w = (const float*)d_in[3];
    const float* t_b = (const float*)d_in[4];
    const float* p_w = (const float*)d_in[5];
    const float* p_b = (const float*)d_in[6];
    const float* W_w = (const float*)d_in[7];
    const float* W_b = (const float*)d_in[8];
    const float* gam = (const float*)d_in[9];
    const float* bet = (const float*)d_in[10];
    float* out = (float*)d_out;
    float* ws = (float*)d_ws;

    short* wall  = (short*)(ws + OFF_WALL);
    short* wall2 = wall + 3 * 32768;
    short* th_t = (short*)(ws + OFF_THT);
    short* ph_t = (short*)(ws + OFF_PHT);
    short* g_t  = (short*)(ws + OFF_GT);
    short* ypart = (short*)(ws + OFF_YP);
    float* mlp = ws + OFF_ML;
    float* mnp = ws + OFF_MEAN;
    float* rsp = ws + OFF_RSTD;

    wconv_kernel<<<512, 256, 0, stream>>>(g_w, t_w, p_w, W_w, wall);
    proj_kernel<<<dim3(N_ / 32, B_), 256, 0, stream>>>(f, wall, t_b, g_b, p_b,
                                                       th_t, g_t, ph_t);
    attn_kernel<<<512, 256, 0, stream>>>(th_t, ph_t, g_t, ypart, mlp);
    wy_merge_kernel<<<dim3(N_ / 32, B_), 256, 0, stream>>>(ypart, mlp, wall2, W_b, out);
    stats_kernel<<<D_, 256, 0, stream>>>(out, mnp, rsp);
    bn_res_kernel<<<(B_ * D_ * N_ / 4) / 256, 256, 0, stream>>>(out, f, mnp, rsp, gam, bet);
}

// Round 6
// 180.012 us; speedup vs baseline: 1.1629x; 1.1629x over previous
//
#include <hip/hip_runtime.h>
#include <hip/hip_bf16.h>
#include <math.h>

#define B_ 2
#define D_ 256
#define N_ 8192
#define CI_ 128
#define M_ 4096
#define BN_EPS_ 1e-5f
#define LOG2E_ 1.4426950408889634f

#define GLOBAL_AS __attribute__((address_space(1)))
#define LDS_AS __attribute__((address_space(3)))

// ---- workspace layout (float offsets) ----
#define OFF_WALL 0                          // bf16 wall[384][256] + wall2[256][128]
#define OFF_THT  65536                      // theta bf16 [B][N][CI]  (pre-scaled by log2 e)
#define OFF_PHT  (OFF_THT + 1048576)        // phi   bf16 [B][M][CI]
#define OFF_GT   (OFF_PHT + 524288)         // g     bf16 [B][CI][M]
#define OFF_YP   (OFF_GT  + 524288)         // y partial bf16 [4][B][N][CI]  (TRANSPOSED)
#define OFF_ML   (OFF_YP  + 4194304)        // m/l fp32 [4][B][2][N]  (m in log2 domain)
#define OFF_MEAN (OFF_ML + 131072)
#define OFF_RSTD (OFF_MEAN + 256)

typedef __attribute__((ext_vector_type(8))) short bfrag;    // 8 bf16 = 4 VGPRs
typedef __attribute__((ext_vector_type(4))) float f4v;      // 16x16 accumulator
typedef __attribute__((ext_vector_type(16))) float f16v;    // 32x32 accumulator
typedef __attribute__((ext_vector_type(4))) short s4v;      // 4 bf16
typedef __attribute__((ext_vector_type(4))) unsigned u4v;   // 4 dwords (reg-only frag build)

__device__ inline unsigned short bf16rne(float x) {
    unsigned u = __float_as_uint(x);
    u += 0x7fff + ((u >> 16) & 1);
    return (unsigned short)(u >> 16);
}

// 2^x via v_exp_f32 directly (no ocml denorm path, no log2e mul)
__device__ inline float exp2fast(float x) {
    float r;
    asm("v_exp_f32 %0, %1" : "=v"(r) : "v"(x));
    return r;
}

// ---------------- pack weights to bf16: wall[384][256] (g|theta|phi), wall2[256][128] (W) ----
// theta weights are pre-scaled by log2(e) so attention softmax runs in exp2 domain.
__global__ __launch_bounds__(256) void wconv_kernel(
    const float* __restrict__ gw, const float* __restrict__ tw, const float* __restrict__ pw,
    const float* __restrict__ Ww, short* __restrict__ wall)
{
    int idx = blockIdx.x * 256 + threadIdx.x;      // 0 .. 131071
    int which = idx >> 15;
    int rem = idx & 32767;
    const float* src = (which == 0) ? gw : (which == 1) ? tw : (which == 2) ? pw : Ww;
    float v = src[rem];
    if (which == 1) v *= LOG2E_;
    wall[idx] = (short)bf16rne(v);
}

// ---------------- MFMA projections ----------------
// Out[cc][n] = sum_d Wall[cc][d] * f[b][d][n], cc in [0,384): g | theta | phi.
// block 256 = 4 waves; wave owns 96 cc (6 frags) x 32 n (2 frags). grid (N/32, B).
__global__ __launch_bounds__(256, 2) void proj_kernel(
    const float* __restrict__ f, const short* __restrict__ wall,
    const float* __restrict__ tb, const float* __restrict__ gb, const float* __restrict__ pb,
    short* __restrict__ th_t, short* __restrict__ g_t, short* __restrict__ ph_t)
{
    __shared__ short sF[32 * 72];   // f chunk transposed [n][k], stride 72 shorts

    const int tid = threadIdx.x;
    const int wave = tid >> 6, lane = tid & 63;
    const int lq = lane & 15, quad = lane >> 4;
    const int b = blockIdx.y;
    const int n0 = blockIdx.x * 32;

    const float* fb = f + (size_t)b * D_ * N_;

    f4v acc[6][2];
#pragma unroll
    for (int ct = 0; ct < 6; ct++)
#pragma unroll
        for (int nf = 0; nf < 2; nf++) acc[ct][nf] = (f4v){0.f, 0.f, 0.f, 0.f};

    const int sn = tid & 31;     // staging: n within tile
    const int sgrp = tid >> 5;   // staging: d' group of 8

    for (int kc = 0; kc < D_; kc += 64) {
        __syncthreads();
#pragma unroll
        for (int jj = 0; jj < 4; jj++) {
            int dd = kc + sgrp * 8 + 2 * jj;
            float v0 = fb[(size_t)dd * N_ + n0 + sn];
            float v1 = fb[(size_t)(dd + 1) * N_ + n0 + sn];
            unsigned pk = (unsigned)bf16rne(v0) | ((unsigned)bf16rne(v1) << 16);
            *(unsigned*)&sF[sn * 72 + sgrp * 8 + 2 * jj] = pk;
        }
        __syncthreads();

        bfrag afr[6][2], bfr[2][2];
#pragma unroll
        for (int ks = 0; ks < 2; ks++) {
#pragma unroll
            for (int nf = 0; nf < 2; nf++)
                bfr[nf][ks] = *(const bfrag*)&sF[(nf * 16 + lq) * 72 + ks * 32 + quad * 8];
#pragma unroll
            for (int ct = 0; ct < 6; ct++)
                afr[ct][ks] = *(const bfrag*)&wall[(wave * 96 + ct * 16 + lq) * 256 + kc + ks * 32 + quad * 8];
        }
#pragma unroll
        for (int ks = 0; ks < 2; ks++)
#pragma unroll
            for (int ct = 0; ct < 6; ct++) {
                acc[ct][0] = __builtin_amdgcn_mfma_f32_16x16x32_bf16(afr[ct][ks], bfr[0][ks], acc[ct][0], 0, 0, 0);
                acc[ct][1] = __builtin_amdgcn_mfma_f32_16x16x32_bf16(afr[ct][ks], bfr[1][ks], acc[ct][1], 0, 0, 0);
            }
    }

#pragma unroll
    for (int ct = 0; ct < 6; ct++) {
        const int cf = wave * 6 + ct;
#pragma unroll
        for (int nf = 0; nf < 2; nf++) {
            f4v v = acc[ct][nf];
            const int n = n0 + nf * 16 + lq;
            if (cf < 8) {                 // g -> pooled, transposed [c][m]
                const int cb = cf * 16 + quad * 4;
                float pl[4];
#pragma unroll
                for (int r = 0; r < 4; r++) {
                    float o = __shfl_xor(v[r], 1);
                    pl[r] = fmaxf(v[r], o) + gb[cb + r];
                }
                if (!(lq & 1)) {
                    const int m = n >> 1;
#pragma unroll
                    for (int r = 0; r < 4; r++)
                        g_t[((size_t)b * CI_ + cb + r) * M_ + m] = (short)bf16rne(pl[r]);
                }
            } else if (cf < 16) {         // theta [n][c], log2e-scaled (weights already scaled)
                const int cb = (cf - 8) * 16 + quad * 4;
                s4v o;
#pragma unroll
                for (int r = 0; r < 4; r++) o[r] = (short)bf16rne(v[r] + tb[cb + r] * LOG2E_);
                *(s4v*)&th_t[((size_t)b * N_ + n) * CI_ + cb] = o;
            } else {                      // phi -> pooled [m][c]
                const int cb = (cf - 16) * 16 + quad * 4;
                float pl[4];
#pragma unroll
                for (int r = 0; r < 4; r++) {
                    float o = __shfl_xor(v[r], 1);
                    pl[r] = fmaxf(v[r], o) + pb[cb + r];
                }
                if (!(lq & 1)) {
                    const int m = n >> 1;
                    s4v o;
#pragma unroll
                    for (int r = 0; r < 4; r++) o[r] = (short)bf16rne(pl[r]);
                    *(s4v*)&ph_t[((size_t)b * M_ + m) * CI_ + cb] = o;
                }
            }
        }
    }
}

// ---------------- MFMA flash attention, 32x32 tiles, key-split 4 ----------------
// block 256 = 4 waves; wave owns 32 q. Q-tile 128, KC=64 keys/chunk, 16 chunks.
// R5 postmortem: g-from-global (per-lane L1 reads, 4x wave redundancy) REGRESSED
// 58.6 -> 84.6 us: L1/VMEM is a worse shared pipe than LDS. R6: g back in LDS via
// DMA, but in the conflict-clean layout that measured ZERO SQ_LDS_BANK_CONFLICT
// in R1/R2: sG[128][72] shorts (144-B rows, 64 data + 8 pad shorts), read at
// slot s*16+h*8, NO xor. DMA writes linearly (base+lane*16), so lane t maps to
// source row=t/9, slot=t%9 (slot 8 = pad, benign over-read). 18 issues/block.
// sPh keeps the R3/R5 XOR-16 scheme (measured conflict-free).
__global__ __launch_bounds__(256, 2) void attn_kernel(
    const short* __restrict__ th_p, const short* __restrict__ ph_p,
    const short* __restrict__ g_p, short* __restrict__ yp, float* __restrict__ ml)
{
    __shared__ short sPh[2][64 * 128];  // phi [key][ci], 256B rows, XOR-16 swizzled slots
    __shared__ short sG [2][128 * 72];  // g^T [c][key], 144B rows (9x16B), no swizzle

    const int tid = threadIdx.x;
    const int wave = tid >> 6, lane = tid & 63;
    const int l = lane & 31, h = lane >> 5;

    // XCD-pinned decomposition: consecutive block ids round-robin across the 8
    // XCDs, and we have exactly 8 (b,split) pairs -> pin pair = bid&7.
    const int bid = blockIdx.x;
    const int b = bid & 1;
    const int split = (bid >> 1) & 3;
    const int q0 = (bid >> 3) * 128;
    const int qg = q0 + wave * 32 + l;

    // theta B-fragments in registers: B[k = 16s + 8h + j][n = q]
    const short* thr = th_p + ((size_t)b * N_ + qg) * CI_;
    bfrag tf[8];
#pragma unroll
    for (int s = 0; s < 8; s++)
        tf[s] = *(const bfrag*)&thr[s * 16 + h * 8];

    f16v yacc[4];
#pragma unroll
    for (int ct = 0; ct < 4; ct++)
#pragma unroll
        for (int r = 0; r < 16; r++) yacc[ct][r] = 0.f;
    float mI = -INFINITY, lI = 0.f;

    const short* phg = ph_p + (size_t)b * M_ * CI_;
    const short* gg  = g_p + (size_t)b * CI_ * M_;

    const int k0 = split * 1024;
    const int xm = l & 15;               // read-side swizzle mask for sPh

    // phi DMA staging: per wave 4 issues x (64 lanes x 16B) = 16 rows.
    const int prow = (lane >> 4);        // phi: row-within-4-group
    const int pslot = lane & 15;         // phi: 16B slot

    // g DMA staging: 18 KB = 18 x 1KB issues; waves 0,1 take 5; waves 2,3 take 4.
    // Lane's dest 16B-slot t = (i0+p)*64 + lane; source row = t/9, slot = t%9
    // (slot 8 is row padding -> harmless over-read of next row / region).
    const int i0 = (wave < 2) ? wave * 5 : 10 + (wave - 2) * 4;
    const int nIss = (wave < 2) ? 5 : 4;
    int gsrc[5];
#pragma unroll
    for (int p = 0; p < 5; p++) {
        const int t = (i0 + p) * 64 + lane;
        gsrc[p] = (t / 9) * M_ + (t % 9) * 8;   // short offset into gg (add KC per chunk)
    }

#define STAGE_DMA(BUF, KC)                                                                  \
    do {                                                                                    \
        _Pragma("unroll")                                                                   \
        for (int p = 0; p < 4; p++) {                                                       \
            const int rp = wave * 16 + p * 4 + prow;          /* row in [0,64) */           \
            const int cg = pslot ^ (p * 4 + prow);            /* swizzled ci-group */       \
            __builtin_amdgcn_global_load_lds(                                               \
                (const GLOBAL_AS void*)(phg + (size_t)((KC) + rp) * 128 + cg * 8),          \
                (LDS_AS void*)(&sPh[BUF][(wave * 16 + p * 4) * 128]), 16, 0, 0);            \
        }                                                                                   \
        _Pragma("unroll")                                                                   \
        for (int p = 0; p < 5; p++) {                                                       \
            if (p < nIss)                                                                   \
                __builtin_amdgcn_global_load_lds(                                           \
                    (const GLOBAL_AS void*)(gg + gsrc[p] + (KC)),                           \
                    (LDS_AS void*)(&sG[BUF][(i0 + p) * 512]), 16, 0, 0);                    \
        }                                                                                   \
    } while (0)

    STAGE_DMA(0, k0);

    int cur = 0;
    for (int kc = k0; kc < k0 + 1024; kc += 64) {
        __syncthreads();                 // drains DMA vmcnt; buf[cur] complete for all waves
        const bool nxt = (kc + 64 < k0 + 1024);
        if (nxt) {
            STAGE_DMA(cur ^ 1, kc + 64); // in-flight across this chunk's compute
            __builtin_amdgcn_sched_barrier(0);   // pin DMA issue before the MFMA region
        }

        // S^T = phi . theta : 2 key-tiles of 32; lane holds col q = l, 16 key-rows/tile
        f16v sv[2];
        __builtin_amdgcn_s_setprio(1);
#pragma unroll
        for (int kt = 0; kt < 2; kt++) {
            f16v a;
#pragma unroll
            for (int r = 0; r < 16; r++) a[r] = 0.f;
#pragma unroll
            for (int s = 0; s < 8; s++) {
                bfrag pa = *(const bfrag*)&sPh[cur][(kt * 32 + l) * 128 + (((s << 1) | h) ^ xm) * 8];
                a = __builtin_amdgcn_mfma_f32_32x32x16_bf16(pa, tf[s], a, 0, 0, 0);
            }
            sv[kt] = a;
        }
        __builtin_amdgcn_s_setprio(0);

        // online softmax for q = l, exp2 domain (keys split across h halves: one shfl)
        float mx = fmaxf(sv[0][0], sv[1][0]);
#pragma unroll
        for (int r = 1; r < 16; r++) mx = fmaxf(mx, fmaxf(sv[0][r], sv[1][r]));
        mx = fmaxf(mx, __shfl_xor(mx, 32));

        // defer-max: only rescale when the running max grew by > 8 (p bounded by 2^8)
        if (__any(mx > mI + 8.f)) {
            float mnew = fmaxf(mI, mx);
            float al = exp2fast(mI - mnew);
            lI *= al;
#pragma unroll
            for (int ct = 0; ct < 4; ct++)
#pragma unroll
                for (int r = 0; r < 16; r++) yacc[ct][r] *= al;
            mI = mnew;
        }

        float ps = 0.f;
        // pack exp2(S) pairs: pw[kt*8 + b2*2 + p] holds keys kt*32 + 8*b2 + 4h + 2p + {0,1}
        unsigned pw[16];
#pragma unroll
        for (int kt = 0; kt < 2; kt++)
#pragma unroll
            for (int i = 0; i < 8; i++) {
                const int r = 2 * i;
                float p0 = exp2fast(sv[kt][r] - mI);
                float p1 = exp2fast(sv[kt][r + 1] - mI);
                ps += p0 + p1;
                unsigned pk;
                asm("v_cvt_pk_bf16_f32 %0, %1, %2" : "=v"(pk) : "v"(p0), "v"(p1));
                pw[kt * 8 + (i >> 1) * 2 + (i & 1)] = pk;
            }
        ps += __shfl_xor(ps, 32);
        lI += ps;

        // P -> B-operand frags: pf[s][j] = P[key = 16s + 8h + j][q = l].
        // value with key k: held at half bit2(k), needed at half bit3(k) -> one shfl_xor(32).
        // All pw[] indices are compile-time constants; h only selects VALUES (cndmask).
        // Register-only build: ext_vector element writes + bit_cast (NO union/address).
        bfrag pf[4];
#pragma unroll
        for (int s = 0; s < 4; s++) {
            const int kt = s >> 1;
            const int iA = kt * 8 + ((2 * s) & 3) * 2;       // block used when h==0 as "own"
            const int iB = kt * 8 + ((2 * s + 1) & 3) * 2;   // block used when h==1 as "own"
            unsigned A0 = pw[iA], A1 = pw[iA + 1];
            unsigned B0 = pw[iB], B1 = pw[iB + 1];
            unsigned O0 = h ? B0 : A0;
            unsigned O1 = h ? B1 : A1;
            unsigned Xs0 = h ? A0 : B0;
            unsigned Xs1 = h ? A1 : B1;
            unsigned X0 = (unsigned)__shfl_xor((int)Xs0, 32);
            unsigned X1 = (unsigned)__shfl_xor((int)Xs1, 32);
            u4v t;
            t.x = h ? X0 : O0;
            t.y = h ? X1 : O1;
            t.z = h ? O0 : X0;
            t.w = h ? O1 : X1;
            pf[s] = __builtin_bit_cast(bfrag, t);
        }

        // PV: y^T += g^T . P  (sG read: 144B rows, slot s*16+h*8 -> conflict-free)
        __builtin_amdgcn_s_setprio(1);
#pragma unroll
        for (int ct = 0; ct < 4; ct++)
#pragma unroll
            for (int s = 0; s < 4; s++) {
                bfrag ga = *(const bfrag*)&sG[cur][(ct * 32 + l) * 72 + s * 16 + h * 8];
                yacc[ct] = __builtin_amdgcn_mfma_f32_32x32x16_bf16(ga, pf[s], yacc[ct], 0, 0, 0);
            }
        __builtin_amdgcn_s_setprio(0);

        cur ^= 1;
    }
#undef STAGE_DMA

    // epilogue: bf16 unnormalized partials TRANSPOSED [n][c] (8B stores) + (m,l)
    short* yb = yp + (((size_t)split * B_ + b) * N_) * CI_;
#pragma unroll
    for (int ct = 0; ct < 4; ct++)
#pragma unroll
        for (int rq = 0; rq < 4; rq++) {
            const int c0 = ct * 32 + 8 * rq + 4 * h;
            s4v o;
#pragma unroll
            for (int j = 0; j < 4; j++) o[j] = (short)bf16rne(yacc[ct][rq * 4 + j]);
            *(s4v*)&yb[(size_t)qg * CI_ + c0] = o;
        }
    if (h == 0) {
        float* mlb = ml + ((split * B_ + b) * 2) * N_;
        mlb[qg] = mI;
        mlb[N_ + qg] = lI;
    }
}

// ---------------- fused merge(4 splits) + Wy MFMA + bias -> d_out ----------------
// out[b][d][n] = Wb[d] + sum_c W[d][c] * y_merged[c][n].
// grid (N/32, B), block 256 = 4 waves; wave w owns d-tiles {2w,2w+1} x 32 n.
// yp is [sp][b][n][c]: per (sp,s) one bfrag (16B) load -> 32 vector loads/thread
// (was 256 scalar ushort loads).
__global__ __launch_bounds__(256) void wy_merge_kernel(
    const short* __restrict__ yp, const float* __restrict__ ml,
    const short* __restrict__ wall2, const float* __restrict__ Wb,
    float* __restrict__ out)
{
    const int tid = threadIdx.x;
    const int wave = tid >> 6, lane = tid & 63;
    const int l = lane & 31, h = lane >> 5;
    const int b = blockIdx.y;
    const int n = blockIdx.x * 32 + l;

    // merge coefficients for this lane's n (m values are log2-domain)
    float m[4], lv[4];
#pragma unroll
    for (int sp = 0; sp < 4; sp++) {
        const float* mlb = ml + ((sp * B_ + b) * 2) * N_;
        m[sp] = mlb[n];
        lv[sp] = mlb[N_ + n];
    }
    float mmax = fmaxf(fmaxf(m[0], m[1]), fmaxf(m[2], m[3]));
    float e[4], den = 0.f;
#pragma unroll
    for (int sp = 0; sp < 4; sp++) { e[sp] = exp2fast(m[sp] - mmax); den += lv[sp] * e[sp]; }
    float inv = 1.0f / den;
#pragma unroll
    for (int sp = 0; sp < 4; sp++) e[sp] *= inv;

    // B-fragments: by[s][j] = y_merged[c = 16s + 8h + j][n]  (vector bfrag loads)
    bfrag by[8];
#pragma unroll
    for (int s = 0; s < 8; s++) {
        float a[8];
#pragma unroll
        for (int j = 0; j < 8; j++) a[j] = 0.f;
#pragma unroll
        for (int sp = 0; sp < 4; sp++) {
            bfrag yv = *(const bfrag*)&yp[(((size_t)sp * B_ + b) * N_ + n) * CI_ + s * 16 + h * 8];
            u4v u = __builtin_bit_cast(u4v, yv);
#pragma unroll
            for (int p = 0; p < 4; p++) {
                a[2 * p]     = fmaf(e[sp], __uint_as_float(u[p] << 16), a[2 * p]);
                a[2 * p + 1] = fmaf(e[sp], __uint_as_float(u[p] & 0xffff0000u), a[2 * p + 1]);
            }
        }
        u4v pk;
#pragma unroll
        for (int p = 0; p < 4; p++) {
            unsigned r;
            asm("v_cvt_pk_bf16_f32 %0, %1, %2" : "=v"(r) : "v"(a[2 * p]), "v"(a[2 * p + 1]));
            pk[p] = r;
        }
        by[s] = __builtin_bit_cast(bfrag, pk);
    }

    f16v acc[2];
#pragma unroll
    for (int rt = 0; rt < 2; rt++)
#pragma unroll
        for (int r = 0; r < 16; r++) acc[rt][r] = 0.f;

#pragma unroll
    for (int s = 0; s < 8; s++)
#pragma unroll
        for (int rt = 0; rt < 2; rt++) {
            bfrag aw = *(const bfrag*)&wall2[((wave * 2 + rt) * 32 + l) * 128 + s * 16 + h * 8];
            acc[rt] = __builtin_amdgcn_mfma_f32_32x32x16_bf16(aw, by[s], acc[rt], 0, 0, 0);
        }

#pragma unroll
    for (int rt = 0; rt < 2; rt++)
#pragma unroll
        for (int r = 0; r < 16; r++) {
            const int d = (wave * 2 + rt) * 32 + (r & 3) + 8 * (r >> 2) + 4 * h;
            out[((size_t)b * D_ + d) * N_ + n] = acc[rt][r] + Wb[d];
        }
}

// ---------------- per-channel batch stats over (b, n) ----------------
__global__ __launch_bounds__(256) void stats_kernel(
    const float* __restrict__ wy, float* __restrict__ mean, float* __restrict__ rstd)
{
    __shared__ float ssum[256], ssq[256];
    int d = blockIdx.x;
    int tid = threadIdx.x;
    float s = 0.f, sq = 0.f;
    for (int b = 0; b < B_; b++) {
        const float4* p = (const float4*)(wy + (size_t)b * D_ * N_ + (size_t)d * N_);
        for (int i = tid; i < N_ / 4; i += 256) {
            float4 v = p[i];
            s += v.x + v.y + v.z + v.w;
            sq = fmaf(v.x, v.x, sq);
            sq = fmaf(v.y, v.y, sq);
            sq = fmaf(v.z, v.z, sq);
            sq = fmaf(v.w, v.w, sq);
        }
    }
    ssum[tid] = s; ssq[tid] = sq;
    __syncthreads();
    for (int st = 128; st > 0; st >>= 1) {
        if (tid < st) { ssum[tid] += ssum[tid + st]; ssq[tid] += ssq[tid + st]; }
        __syncthreads();
    }
    if (tid == 0) {
        float inv = 1.0f / (float)(B_ * N_);
        float mn = ssum[0] * inv;
        float var = ssq[0] * inv - mn * mn;
        mean[d] = mn;
        rstd[d] = rsqrtf(var + BN_EPS_);
    }
}

// ---------------- BN (affine) + residual, in-place on d_out ----------------
__global__ __launch_bounds__(256) void bn_res_kernel(
    float* __restrict__ out, const float* __restrict__ f,
    const float* __restrict__ mean, const float* __restrict__ rstd,
    const float* __restrict__ gamma, const float* __restrict__ beta)
{
    int i = blockIdx.x * 256 + threadIdx.x;
    size_t e = (size_t)i * 4;
    int d = (int)((e >> 13) & 255);
    float4 wy = ((const float4*)out)[i];
    float4 ff = ((const float4*)f)[i];
    float sc = rstd[d] * gamma[d];
    float mn = mean[d];
    float bt = beta[d];
    float4 r;
    r.x = (wy.x - mn) * sc + bt + ff.x;
    r.y = (wy.y - mn) * sc + bt + ff.y;
    r.z = (wy.z - mn) * sc + bt + ff.z;
    r.w = (wy.w - mn) * sc + bt + ff.w;
    ((float4*)out)[i] = r;
}

extern "C" void kernel_launch(void* const* d_in, const int* in_sizes, int n_in,
                              void* d_out, int out_size, void* d_ws, size_t ws_size,
                              hipStream_t stream)
{
    const float* f   = (const float*)d_in[0];
    const float* g_w = (const float*)d_in[1];
    const float* g_b = (const float*)d_in[2];
    const float* t_w = (const float*)d_in[3];
    const float* t_b = (const float*)d_in[4];
    const float* p_w = (const float*)d_in[5];
    const float* p_b = (const float*)d_in[6];
    const float* W_w = (const float*)d_in[7];
    const float* W_b = (const float*)d_in[8];
    const float* gam = (const float*)d_in[9];
    const float* bet = (const float*)d_in[10];
    float* out = (float*)d_out;
    float* ws = (float*)d_ws;

    short* wall  = (short*)(ws + OFF_WALL);
    short* wall2 = wall + 3 * 32768;
    short* th_t = (short*)(ws + OFF_THT);
    short* ph_t = (short*)(ws + OFF_PHT);
    short* g_t  = (short*)(ws + OFF_GT);
    short* ypart = (short*)(ws + OFF_YP);
    float* mlp = ws + OFF_ML;
    float* mnp = ws + OFF_MEAN;
    float* rsp = ws + OFF_RSTD;

    wconv_kernel<<<512, 256, 0, stream>>>(g_w, t_w, p_w, W_w, wall);
    proj_kernel<<<dim3(N_ / 32, B_), 256, 0, stream>>>(f, wall, t_b, g_b, p_b,
                                                       th_t, g_t, ph_t);
    attn_kernel<<<512, 256, 0, stream>>>(th_t, ph_t, g_t, ypart, mlp);
    wy_merge_kernel<<<dim3(N_ / 32, B_), 256, 0, stream>>>(ypart, mlp, wall2, W_b, out);
    stats_kernel<<<D_, 256, 0, stream>>>(out, mnp, rsp);
    bn_res_kernel<<<(B_ * D_ * N_ / 4) / 256, 256, 0, stream>>>(out, f, mnp, rsp, gam, bet);
}